// Round 6
// baseline (622.334 us; speedup 1.0000x reference)
//
#include <hip/hip_runtime.h>
#include <stdint.h>

typedef unsigned short u16;
typedef unsigned int u32;
typedef short s16x8 __attribute__((ext_vector_type(8)));    // staging
typedef __bf16 bfv8 __attribute__((ext_vector_type(8)));    // MFMA operands
typedef float f32x4 __attribute__((ext_vector_type(4)));

#define S_LEN 2048
#define HID 4096
#define NQKV 6144

#define MFMA16(d, a, b) (d) = __builtin_amdgcn_mfma_f32_16x16x32_bf16((a), (b), (d), 0, 0, 0)

__device__ __forceinline__ u16 f2bf(float f){
  u32 u = __float_as_uint(f);
  return (u16)((u + 0x7fffu + ((u >> 16) & 1u)) >> 16);   // RNE
}
__device__ __forceinline__ float bf2f(u16 x){
  return __uint_as_float((u32)x << 16);
}

// async global->LDS, 16B per lane. LDS dest is wave-uniform base; HW writes
// lane i at ldsbase + i*16. Global src is per-lane.
__device__ __forceinline__ void gl16(const u16* g, u16* l){
  __builtin_amdgcn_global_load_lds((const __attribute__((address_space(1))) u32*)g,
                                   (__attribute__((address_space(3))) u32*)l,
                                   16, 0, 0);
}

// ---------------- fp32 -> bf16 cast, 4 elems/thread ----------------
__global__ __launch_bounds__(256) void cvt_bf16(const float* __restrict__ in,
                                                u16* __restrict__ out, int n4){
  int i = blockIdx.x * 256 + threadIdx.x;
  if (i >= n4) return;
  float4 v = ((const float4*)in)[i];
  ushort4 o;
  o.x = f2bf(v.x); o.y = f2bf(v.y); o.z = f2bf(v.z); o.w = f2bf(v.w);
  ((ushort4*)out)[i] = o;
}

// ---------------- bf16 GEMM: C[M][N] = A[M][K] * B[N][K]^T ----------------
// 128x128 tile, BK=32, 256 threads (4 waves 2x2), 16x16x32 MFMA.
// global_load_lds width-16 staging into double-buffered LINEAR LDS (m97 structure).
template<typename OT>
__global__ __launch_bounds__(256) void gemm_bt(const u16* __restrict__ A,
                                               const u16* __restrict__ B,
                                               OT* __restrict__ C, int N, int K){
  __shared__ __align__(16) u16 As[2][128*32];
  __shared__ __align__(16) u16 Bs[2][128*32];
  const int tid = threadIdx.x;
  const int lane = tid & 63, wave = tid >> 6;
  const int g = lane >> 4, l16 = lane & 15;
  const int wr = wave >> 1, wc = wave & 1;
  const u16* Ag = A + (size_t)blockIdx.y * 128 * K;
  const u16* Bg = B + (size_t)blockIdx.x * 128 * K;
  const int r0 = wave*32 + (lane >> 2);
  const int r1 = r0 + 16;
  const int su = lane & 3;
  const int l0 = wave*1024;        // elem offset of chunk0 dest
  const int l1 = wave*1024 + 512;  // elem offset of chunk1 dest
  f32x4 acc[4][4] = {};

#define ISSUE(b, k0)                                          \
  gl16(Ag + (size_t)r0*K + (k0) + su*8, &As[b][l0]);          \
  gl16(Ag + (size_t)r1*K + (k0) + su*8, &As[b][l1]);          \
  gl16(Bg + (size_t)r0*K + (k0) + su*8, &Bs[b][l0]);          \
  gl16(Bg + (size_t)r1*K + (k0) + su*8, &Bs[b][l1]);

  ISSUE(0, 0)
  __syncthreads();                 // vmcnt(0) drain + barrier
  const int KIT = K >> 5;
  for (int it = 0; it < KIT; it++){
    const int b = it & 1;
    if (it + 1 < KIT){ ISSUE(b^1, (it+1)*32) }
    bfv8 af[4], bfr[4];
    #pragma unroll
    for (int i = 0; i < 4; i++)
      af[i] = *(const bfv8*)&As[b][(wr*64 + i*16 + l16)*32 + g*8];
    #pragma unroll
    for (int j = 0; j < 4; j++)
      bfr[j] = *(const bfv8*)&Bs[b][(wc*64 + j*16 + l16)*32 + g*8];
    #pragma unroll
    for (int i = 0; i < 4; i++)
      #pragma unroll
      for (int j = 0; j < 4; j++)
        MFMA16(acc[i][j], af[i], bfr[j]);
    __syncthreads();               // drains next-tile loads + syncs buffers
  }
#undef ISSUE
  OT* Cp = C + (size_t)(blockIdx.y*128 + wr*64) * N + blockIdx.x*128 + wc*64;
  #pragma unroll
  for (int i = 0; i < 4; i++)
    #pragma unroll
    for (int j = 0; j < 4; j++)
      #pragma unroll
      for (int r = 0; r < 4; r++){
        float v = acc[i][j][r];
        if constexpr (sizeof(OT) == 2)
          Cp[(size_t)(i*16 + g*4 + r) * N + j*16 + l16] = f2bf(v);
        else
          Cp[(size_t)(i*16 + g*4 + r) * N + j*16 + l16] = v;
      }
}

// ---------------- RoPE + head-major reorg (q and k), fp32 math, bf16 in/out ----------------
__global__ __launch_bounds__(256) void rope_reorg(const u16* __restrict__ qkv,
                                                  const int* __restrict__ pos,
                                                  u16* __restrict__ Qb, u16* __restrict__ Kb){
  const int hh = blockIdx.x;
  const int s  = blockIdx.y*4 + (threadIdx.x >> 6);
  const int j  = threadIdx.x & 63;
  const float p = (float)pos[s];
  const float inv = __expf(-(float)j * (13.815510557964274f / 64.0f)); // 1e6^(-j/64)
  float sn, cs;
  sincosf(p * inv, &sn, &cs);
  const u16* src;
  u16* dst;
  if (hh < 32){
    src = qkv + (size_t)s*NQKV + (hh >> 2)*768 + (hh & 3)*128;
    dst = Qb + ((size_t)hh*S_LEN + s)*128;
  } else {
    int h = hh - 32;
    src = qkv + (size_t)s*NQKV + h*768 + 512;
    dst = Kb + ((size_t)h*S_LEN + s)*128;
  }
  float x1 = bf2f(src[j]), x2 = bf2f(src[j + 64]);
  dst[j]      = f2bf(x1*cs - x2*sn);
  dst[j + 64] = f2bf(x2*cs + x1*sn);
}

// ---------------- V: qkv[s][.] bf16 -> Vt[h][d][s] bf16, 64x64 LDS tile transpose ----------------
__global__ __launch_bounds__(256) void v_transpose(const u16* __restrict__ qkv,
                                                   u16* __restrict__ Vt){
  __shared__ u16 T[64][72];
  const int st = blockIdx.x, dt = blockIdx.y, h = blockIdx.z;
  const int w = threadIdx.x >> 6, lane = threadIdx.x & 63;
  const int s0 = st*64, d0 = dt*64;
  #pragma unroll
  for (int i = 0; i < 16; i++){
    int sl = w*16 + i;
    T[sl][lane] = qkv[(size_t)(s0+sl)*NQKV + h*768 + 640 + d0 + lane];
  }
  __syncthreads();
  #pragma unroll
  for (int i = 0; i < 16; i++){
    int dl = w*16 + i;
    Vt[((size_t)h*128 + d0 + dl)*S_LEN + s0 + lane] = T[lane][dl];
  }
}

// ---------------- causal GQA flash attention ----------------
// grid (32 heads, 32 qblocks REVERSED), 256 threads (4 waves x 16 q-rows).
// K: async gl_lds staged, double-buffered, pre-swizzled source (rule #21).
// V: read direct from global (L2/L3-resident; Vt rows are contiguous in s).
// ONE barrier per KV tile.
__global__ __launch_bounds__(256) void attn_fwd(const u16* __restrict__ Q,
                                                const u16* __restrict__ K,
                                                const u16* __restrict__ V,
                                                u16* __restrict__ O){
  __shared__ __align__(16) u16 Ks[2][64*128];  // linear dest; G-col pre-swizzled
  __shared__ __align__(16) u16 Ps[4][16][72];  // per-wave P; 144B row pitch
  const int hq = blockIdx.x;                   // head on x (fast dim)
  const int qblk = 31 - blockIdx.y;            // longest-first
  const int hk = hq >> 2;
  const int tid = threadIdx.x, lane = tid & 63, w = tid >> 6;
  const int g = lane >> 4, l16 = lane & 15;
  const int q0 = qblk*64 + w*16;
  const u16* Qg = Q + ((size_t)hq*S_LEN + q0 + l16)*128;
  bfv8 qf[4];
  #pragma unroll
  for (int kk = 0; kk < 4; kk++) qf[kk] = *(const bfv8*)(Qg + kk*32 + g*8);
  const u16* Kg = K + (size_t)hk*S_LEN*128;
  const u16* Vg = V + (size_t)hk*128*S_LEN;
  f32x4 oacc[8] = {};
  float m_run[4], l_run[4];
  #pragma unroll
  for (int r = 0; r < 4; r++){ m_run[r] = -1e30f; l_run[r] = 0.0f; }
  const float scale = 0.08838834764831845f;  // 1/sqrt(128)

  // K staging: 4 issues/thread. Issue i: wave w covers local rows i*16+w*4..+3.
  // lane l -> local row rl = i*16 + w*4 + (l>>4), LDS unit u = l&15 (linear).
  // source col-unit pre-swizzled: u ^ (rl&7)  => LDS[r][u] = G[r][u^(r&7)].
  const int krow = w*4 + (lane >> 4);          // local row for i=0 (rl = i*16+krow)
  const int ksrc = ((lane & 15) ^ (krow & 7)); // pre-swizzled source unit (i*16%8==0)

#define ISSUE_K(t, b)                                                             \
  _Pragma("unroll")                                                               \
  for (int i = 0; i < 4; i++)                                                     \
    gl16(Kg + ((size_t)((t)*64 + i*16 + krow))*128 + ksrc*8,                      \
         &Ks[b][(i*16 + w*4)*128]);

  ISSUE_K(0, 0)
  __syncthreads();                             // drain prologue loads

  for (int t = 0; t <= qblk; t++){
    const int b = t & 1;
    if (t < qblk){ ISSUE_K(t+1, b^1) }
    // ---- QK^T : wave computes its 16 q-rows x 64 kv ----
    f32x4 sacc[4] = {};
    #pragma unroll
    for (int j = 0; j < 4; j++){
      int row = j*16 + l16;
      #pragma unroll
      for (int kk = 0; kk < 4; kk++){
        bfv8 kf = *(const bfv8*)&Ks[b][row*128 + ((kk*4 + g) ^ (row & 7))*8];
        MFMA16(sacc[j], qf[kk], kf);
      }
    }
    float sc[4][4];
    #pragma unroll
    for (int j = 0; j < 4; j++)
      #pragma unroll
      for (int r = 0; r < 4; r++)
        sc[j][r] = sacc[j][r] * scale;
    if (t == qblk){
      #pragma unroll
      for (int j = 0; j < 4; j++){
        int kvc = t*64 + j*16 + l16;
        #pragma unroll
        for (int r = 0; r < 4; r++)
          if (kvc > q0 + g*4 + r) sc[j][r] = -1e30f;
      }
    }
    // ---- online softmax (row = g*4+r; reduce over l16 within g-group) ----
    float mx[4];
    #pragma unroll
    for (int r = 0; r < 4; r++)
      mx[r] = fmaxf(fmaxf(sc[0][r], sc[1][r]), fmaxf(sc[2][r], sc[3][r]));
    #pragma unroll
    for (int off = 1; off < 16; off <<= 1)
      #pragma unroll
      for (int r = 0; r < 4; r++)
        mx[r] = fmaxf(mx[r], __shfl_xor(mx[r], off));
    float sf[4], pr[4][4], rsum[4];
    #pragma unroll
    for (int r = 0; r < 4; r++){
      float mn = fmaxf(m_run[r], mx[r]);
      sf[r] = __expf(m_run[r] - mn);
      m_run[r] = mn;
    }
    #pragma unroll
    for (int j = 0; j < 4; j++)
      #pragma unroll
      for (int r = 0; r < 4; r++)
        pr[j][r] = __expf(sc[j][r] - m_run[r]);
    #pragma unroll
    for (int r = 0; r < 4; r++)
      rsum[r] = (pr[0][r] + pr[1][r]) + (pr[2][r] + pr[3][r]);
    #pragma unroll
    for (int off = 1; off < 16; off <<= 1)
      #pragma unroll
      for (int r = 0; r < 4; r++)
        rsum[r] += __shfl_xor(rsum[r], off);
    #pragma unroll
    for (int r = 0; r < 4; r++)
      l_run[r] = l_run[r]*sf[r] + rsum[r];
    #pragma unroll
    for (int n = 0; n < 8; n++)
      #pragma unroll
      for (int r = 0; r < 4; r++)
        oacc[n][r] *= sf[r];
    // ---- P: C-layout -> A-layout via per-wave LDS (intra-wave, no barrier) ----
    #pragma unroll
    for (int j = 0; j < 4; j++)
      #pragma unroll
      for (int r = 0; r < 4; r++)
        Ps[w][g*4 + r][j*16 + l16] = f2bf(pr[j][r]);
    bfv8 pf[2];
    #pragma unroll
    for (int kk = 0; kk < 2; kk++)
      pf[kk] = *(const bfv8*)&Ps[w][l16][kk*32 + g*8];
    // ---- PV: O[q][d] += P[q][s] * Vt[d][s], V direct from global ----
    #pragma unroll
    for (int n = 0; n < 8; n++){
      int drow = n*16 + l16;
      #pragma unroll
      for (int kk = 0; kk < 2; kk++){
        bfv8 vf = *(const bfv8*)(Vg + (size_t)drow*S_LEN + t*64 + kk*32 + g*8);
        MFMA16(oacc[n], pf[kk], vf);
      }
    }
    __syncthreads();   // single barrier: drains next-tile K loads, syncs buffers
  }
#undef ISSUE_K
  #pragma unroll
  for (int r = 0; r < 4; r++){
    float invl = 1.0f / l_run[r];
    #pragma unroll
    for (int n = 0; n < 8; n++)
      O[(size_t)(q0 + g*4 + r)*HID + hq*128 + n*16 + l16] = f2bf(oacc[n][r]*invl);
  }
}

// ---------------- launch ----------------
extern "C" void kernel_launch(void* const* d_in, const int* in_sizes, int n_in,
                              void* d_out, int out_size, void* d_ws, size_t ws_size,
                              hipStream_t stream){
  const float* hidden = (const float*)d_in[0];
  const float* wqkv   = (const float*)d_in[1];
  const float* wo     = (const float*)d_in[2];
  const int*   pos    = (const int*)d_in[4];
  float* out = (float*)d_out;
  char* ws = (char*)d_ws;

  // workspace layout (112 MiB total)
  u16* hB    = (u16*)(ws);                    // [0,16)   hidden bf16
  u16* wqkvB = (u16*)(ws + (16ull<<20));      // [16,64)  wqkv bf16 (dead after gemm1)
  u16* woB   = (u16*)(ws + (16ull<<20));      // [16,48)  alias: wo bf16
  u16* qkvB  = (u16*)(ws + (64ull<<20));      // [64,88)  qkv bf16 (dead after rope+vt)
  u16* attnB = (u16*)(ws + (64ull<<20));      // [64,80)  alias: attn out bf16
  u16* Qb    = (u16*)(ws + (88ull<<20));      // [88,104)
  u16* Kb    = (u16*)(ws + (104ull<<20));     // [104,108)
  u16* Vtb   = (u16*)(ws + (108ull<<20));     // [108,112)

  cvt_bf16<<<dim3(8192),  256, 0, stream>>>(hidden, hB, 2097152);
  cvt_bf16<<<dim3(24576), 256, 0, stream>>>(wqkv, wqkvB, 6291456);
  gemm_bt<u16><<<dim3(48,16), 256, 0, stream>>>(hB, wqkvB, qkvB, NQKV, HID);
  cvt_bf16<<<dim3(16384), 256, 0, stream>>>(wo, woB, 4194304);   // overwrites wqkvB (dead)
  rope_reorg<<<dim3(40,512), 256, 0, stream>>>(qkvB, pos, Qb, Kb);
  v_transpose<<<dim3(32,2,8), 256, 0, stream>>>(qkvB, Vtb);
  attn_fwd<<<dim3(32,32), 256, 0, stream>>>(Qb, Kb, Vtb, attnB);
  gemm_bt<float><<<dim3(32,16), 256, 0, stream>>>(attnB, woB, out, HID, HID);
}

// Round 8
// 530.629 us; speedup vs baseline: 1.1728x; 1.1728x over previous
//
#include <hip/hip_runtime.h>
#include <stdint.h>

typedef unsigned short u16;
typedef unsigned int u32;
typedef short s16x8 __attribute__((ext_vector_type(8)));    // staging
typedef __bf16 bfv8 __attribute__((ext_vector_type(8)));    // MFMA operands
typedef float f32x4 __attribute__((ext_vector_type(4)));

#define S_LEN 2048
#define HID 4096
#define NQKV 6144

#define MFMA16(d, a, b) (d) = __builtin_amdgcn_mfma_f32_16x16x32_bf16((a), (b), (d), 0, 0, 0)

// native f32->bf16 (hardware v_cvt, RNE) — compiler packs pairs
__device__ __forceinline__ u16 f2b(float f){
  __bf16 h = (__bf16)f;
  return __builtin_bit_cast(u16, h);
}
__device__ __forceinline__ float bf2f(u16 x){
  return __uint_as_float((u32)x << 16);
}

// async global->LDS, 16B per lane. LDS dest is wave-uniform base; HW writes
// lane i at ldsbase + i*16. Global src is per-lane.
__device__ __forceinline__ void gl16(const u16* g, u16* l){
  __builtin_amdgcn_global_load_lds((const __attribute__((address_space(1))) u32*)g,
                                   (__attribute__((address_space(3))) u32*)l,
                                   16, 0, 0);
}

// ---------------- fp32 -> bf16 cast, 4 elems/thread ----------------
__global__ __launch_bounds__(256) void cvt_bf16(const float* __restrict__ in,
                                                u16* __restrict__ out, int n4){
  int i = blockIdx.x * 256 + threadIdx.x;
  if (i >= n4) return;
  float4 v = ((const float4*)in)[i];
  ushort4 o;
  o.x = f2b(v.x); o.y = f2b(v.y); o.z = f2b(v.z); o.w = f2b(v.w);
  ((ushort4*)out)[i] = o;
}

// ---------------- bf16 GEMM: C[M][N] = A[M][K] * B[N][K]^T ----------------
// 128x128 tile, BK=32, 256 threads (4 waves 2x2), 16x16x32 MFMA.
// global_load_lds width-16 staging into double-buffered LINEAR LDS (m97 structure).
template<typename OT>
__global__ __launch_bounds__(256) void gemm_bt(const u16* __restrict__ A,
                                               const u16* __restrict__ B,
                                               OT* __restrict__ C, int N, int K){
  __shared__ __align__(16) u16 As[2][128*32];
  __shared__ __align__(16) u16 Bs[2][128*32];
  const int tid = threadIdx.x;
  const int lane = tid & 63, wave = tid >> 6;
  const int g = lane >> 4, l16 = lane & 15;
  const int wr = wave >> 1, wc = wave & 1;
  const u16* Ag = A + (size_t)blockIdx.y * 128 * K;
  const u16* Bg = B + (size_t)blockIdx.x * 128 * K;
  const int r0 = wave*32 + (lane >> 2);
  const int r1 = r0 + 16;
  const int su = lane & 3;
  const int l0 = wave*1024;        // elem offset of chunk0 dest
  const int l1 = wave*1024 + 512;  // elem offset of chunk1 dest
  f32x4 acc[4][4] = {};

#define ISSUE(b, k0)                                          \
  gl16(Ag + (size_t)r0*K + (k0) + su*8, &As[b][l0]);          \
  gl16(Ag + (size_t)r1*K + (k0) + su*8, &As[b][l1]);          \
  gl16(Bg + (size_t)r0*K + (k0) + su*8, &Bs[b][l0]);          \
  gl16(Bg + (size_t)r1*K + (k0) + su*8, &Bs[b][l1]);

  ISSUE(0, 0)
  __syncthreads();                 // vmcnt(0) drain + barrier
  const int KIT = K >> 5;
  for (int it = 0; it < KIT; it++){
    const int b = it & 1;
    if (it + 1 < KIT){ ISSUE(b^1, (it+1)*32) }
    bfv8 af[4], bfr[4];
    #pragma unroll
    for (int i = 0; i < 4; i++)
      af[i] = *(const bfv8*)&As[b][(wr*64 + i*16 + l16)*32 + g*8];
    #pragma unroll
    for (int j = 0; j < 4; j++)
      bfr[j] = *(const bfv8*)&Bs[b][(wc*64 + j*16 + l16)*32 + g*8];
    #pragma unroll
    for (int i = 0; i < 4; i++)
      #pragma unroll
      for (int j = 0; j < 4; j++)
        MFMA16(acc[i][j], af[i], bfr[j]);
    __syncthreads();               // drains next-tile loads + syncs buffers
  }
#undef ISSUE
  OT* Cp = C + (size_t)(blockIdx.y*128 + wr*64) * N + blockIdx.x*128 + wc*64;
  #pragma unroll
  for (int i = 0; i < 4; i++)
    #pragma unroll
    for (int j = 0; j < 4; j++)
      #pragma unroll
      for (int r = 0; r < 4; r++){
        float v = acc[i][j][r];
        if constexpr (sizeof(OT) == 2)
          Cp[(size_t)(i*16 + g*4 + r) * N + j*16 + l16] = f2b(v);
        else
          Cp[(size_t)(i*16 + g*4 + r) * N + j*16 + l16] = v;
      }
}

// ---------------- RoPE + head-major reorg, ONE sincos per (s,j) ----------------
// grid (512), block 256 (4 s-rows x 64 j-lanes). Loops all 32 q-heads + 8 k-heads.
__global__ __launch_bounds__(256) void rope_reorg(const u16* __restrict__ qkv,
                                                  const int* __restrict__ pos,
                                                  u16* __restrict__ Qb, u16* __restrict__ Kb){
  const int s = blockIdx.x*4 + (threadIdx.x >> 6);
  const int j = threadIdx.x & 63;
  const float p = (float)pos[s];
  const float inv = __expf(-(float)j * (13.815510557964274f / 64.0f)); // 1e6^(-j/64)
  float sn, cs;
  __sincosf(p * inv, &sn, &cs);
  const u16* base = qkv + (size_t)s*NQKV;
  #pragma unroll 4
  for (int hh = 0; hh < 32; hh++){
    const u16* src = base + (hh >> 2)*768 + (hh & 3)*128;
    u16* dst = Qb + ((size_t)hh*S_LEN + s)*128;
    float x1 = bf2f(src[j]), x2 = bf2f(src[j + 64]);
    dst[j]      = f2b(x1*cs - x2*sn);
    dst[j + 64] = f2b(x2*cs + x1*sn);
  }
  #pragma unroll 4
  for (int h = 0; h < 8; h++){
    const u16* src = base + h*768 + 512;
    u16* dst = Kb + ((size_t)h*S_LEN + s)*128;
    float x1 = bf2f(src[j]), x2 = bf2f(src[j + 64]);
    dst[j]      = f2b(x1*cs - x2*sn);
    dst[j + 64] = f2b(x2*cs + x1*sn);
  }
}

// ---------------- V: qkv[s][.] bf16 -> Vt[h][d][s] bf16, 64x64 LDS tile transpose ----------------
__global__ __launch_bounds__(256) void v_transpose(const u16* __restrict__ qkv,
                                                   u16* __restrict__ Vt){
  __shared__ u16 T[64][72];
  const int st = blockIdx.x, dt = blockIdx.y, h = blockIdx.z;
  const int w = threadIdx.x >> 6, lane = threadIdx.x & 63;
  const int s0 = st*64, d0 = dt*64;
  #pragma unroll
  for (int i = 0; i < 16; i++){
    int sl = w*16 + i;
    T[sl][lane] = qkv[(size_t)(s0+sl)*NQKV + h*768 + 640 + d0 + lane];
  }
  __syncthreads();
  #pragma unroll
  for (int i = 0; i < 16; i++){
    int dl = w*16 + i;
    Vt[((size_t)h*128 + d0 + dl)*S_LEN + s0 + lane] = T[lane][dl];
  }
}

// ---------------- causal GQA flash attention ----------------
// grid (32 heads, 32 qblocks REVERSED = longest-first), 256 threads (4 waves x 16 q-rows).
// Round-5 proven structure: K+V reg-staged into single LDS buffers, 2 barriers/tile.
// Adds: T13 defer-rescale (THR=8), native bf16 cvt in P path.
__global__ __launch_bounds__(256) void attn_fwd(const u16* __restrict__ Q,
                                                const u16* __restrict__ K,
                                                const u16* __restrict__ V,
                                                u16* __restrict__ O){
  __shared__ __align__(16) u16 Ks[64*128];     // [kv][d], XOR-swizzled 16B units
  __shared__ __align__(16) u16 Vs[128*64];     // [d][kv], XOR-swizzled
  __shared__ __align__(16) u16 Ps[4][16][72];  // per-wave P; 144B row pitch
  const int hq = blockIdx.x;                   // head on x (fast dim)
  const int qblk = 31 - blockIdx.y;            // longest-first
  const int hk = hq >> 2;
  const int tid = threadIdx.x, lane = tid & 63, w = tid >> 6;
  const int g = lane >> 4, l16 = lane & 15;
  const int q0 = qblk*64 + w*16;
  const u16* Qg = Q + ((size_t)hq*S_LEN + q0 + l16)*128;
  bfv8 qf[4];
  #pragma unroll
  for (int kk = 0; kk < 4; kk++) qf[kk] = *(const bfv8*)(Qg + kk*32 + g*8);
  const u16* Kg = K + (size_t)hk*S_LEN*128;
  const u16* Vg = V + (size_t)hk*128*S_LEN;
  f32x4 oacc[8] = {};
  float m_run[4], l_run[4];
  #pragma unroll
  for (int r = 0; r < 4; r++){ m_run[r] = -1e30f; l_run[r] = 0.0f; }
  const float scale = 0.08838834764831845f;  // 1/sqrt(128)

  const int rowk = w*16 + (lane >> 4);       // K staging rows: +{0,4,8,12}
  const int rowv = w*32 + (lane >> 3);       // V staging rows: +{0,8,16,24}

#define KV_LOAD(t, kr, vr)                                                        \
  _Pragma("unroll")                                                               \
  for (int i = 0; i < 4; i++){                                                    \
    kr[i] = *(const s16x8*)(Kg + ((size_t)((t)*64 + rowk + i*4))*128 + (lane & 15)*8); \
    vr[i] = *(const s16x8*)(Vg + (size_t)(rowv + i*8)*S_LEN + (t)*64 + (lane & 7)*8);  \
  }
#define KV_STORE(kr, vr)                                                          \
  _Pragma("unroll")                                                               \
  for (int i = 0; i < 4; i++){                                                    \
    int rk = rowk + i*4, rv = rowv + i*8;                                         \
    *(s16x8*)&Ks[rk*128 + ((lane & 15) ^ (rk & 7))*8] = kr[i];                    \
    *(s16x8*)&Vs[rv*64  + ((lane & 7)  ^ (rv & 7))*8] = vr[i];                    \
  }

  {
    s16x8 kr[4], vr[4];
    KV_LOAD(0, kr, vr)
    KV_STORE(kr, vr)
  }
  __syncthreads();

  for (int t = 0; t <= qblk; t++){
    s16x8 nkr[4], nvr[4];
    if (t + 1 <= qblk){ KV_LOAD(t+1, nkr, nvr) }
    // ---- QK^T : wave computes its 16 q-rows x 64 kv ----
    f32x4 sacc[4] = {};
    #pragma unroll
    for (int j = 0; j < 4; j++){
      int row = j*16 + l16;
      #pragma unroll
      for (int kk = 0; kk < 4; kk++){
        bfv8 kf = *(const bfv8*)&Ks[row*128 + ((kk*4 + g) ^ (row & 7))*8];
        MFMA16(sacc[j], qf[kk], kf);
      }
    }
    float sc[4][4];
    #pragma unroll
    for (int j = 0; j < 4; j++)
      #pragma unroll
      for (int r = 0; r < 4; r++)
        sc[j][r] = sacc[j][r] * scale;
    if (t == qblk){
      #pragma unroll
      for (int j = 0; j < 4; j++){
        int kvc = t*64 + j*16 + l16;
        #pragma unroll
        for (int r = 0; r < 4; r++)
          if (kvc > q0 + g*4 + r) sc[j][r] = -1e30f;
      }
    }
    // ---- online softmax (row = g*4+r; reduce over l16 within g-group) ----
    float mx[4];
    #pragma unroll
    for (int r = 0; r < 4; r++)
      mx[r] = fmaxf(fmaxf(sc[0][r], sc[1][r]), fmaxf(sc[2][r], sc[3][r]));
    #pragma unroll
    for (int off = 1; off < 16; off <<= 1)
      #pragma unroll
      for (int r = 0; r < 4; r++)
        mx[r] = fmaxf(mx[r], __shfl_xor(mx[r], off));
    // T13: defer the O-rescale unless the running max grew by > 8
    bool need = false;
    #pragma unroll
    for (int r = 0; r < 4; r++) need |= (mx[r] > m_run[r] + 8.0f);
    if (__any(need)){
      float sf[4];
      #pragma unroll
      for (int r = 0; r < 4; r++){
        float mn = fmaxf(m_run[r], mx[r]);
        sf[r] = __expf(m_run[r] - mn);
        m_run[r] = mn;
        l_run[r] *= sf[r];
      }
      #pragma unroll
      for (int n = 0; n < 8; n++)
        #pragma unroll
        for (int r = 0; r < 4; r++)
          oacc[n][r] *= sf[r];
    }
    float pr[4][4], rsum[4];
    #pragma unroll
    for (int j = 0; j < 4; j++)
      #pragma unroll
      for (int r = 0; r < 4; r++)
        pr[j][r] = __expf(sc[j][r] - m_run[r]);
    #pragma unroll
    for (int r = 0; r < 4; r++)
      rsum[r] = (pr[0][r] + pr[1][r]) + (pr[2][r] + pr[3][r]);
    #pragma unroll
    for (int off = 1; off < 16; off <<= 1)
      #pragma unroll
      for (int r = 0; r < 4; r++)
        rsum[r] += __shfl_xor(rsum[r], off);
    #pragma unroll
    for (int r = 0; r < 4; r++)
      l_run[r] += rsum[r];
    // ---- P: C-layout -> A-layout via per-wave LDS (intra-wave, no barrier) ----
    #pragma unroll
    for (int j = 0; j < 4; j++)
      #pragma unroll
      for (int r = 0; r < 4; r++)
        Ps[w][g*4 + r][j*16 + l16] = f2b(pr[j][r]);
    bfv8 pf[2];
    #pragma unroll
    for (int kk = 0; kk < 2; kk++)
      pf[kk] = *(const bfv8*)&Ps[w][l16][kk*32 + g*8];
    // ---- PV: O[q][d] += P[q][s] * Vt[d][s] ----
    #pragma unroll
    for (int n = 0; n < 8; n++){
      int drow = n*16 + l16;
      #pragma unroll
      for (int kk = 0; kk < 2; kk++){
        bfv8 vf = *(const bfv8*)&Vs[drow*64 + ((kk*4 + g) ^ (drow & 7))*8];
        MFMA16(oacc[n], pf[kk], vf);
      }
    }
    __syncthreads();
    if (t + 1 <= qblk){ KV_STORE(nkr, nvr) }
    __syncthreads();
  }
#undef KV_LOAD
#undef KV_STORE
  #pragma unroll
  for (int r = 0; r < 4; r++){
    float invl = 1.0f / l_run[r];
    #pragma unroll
    for (int n = 0; n < 8; n++)
      O[(size_t)(q0 + g*4 + r)*HID + hq*128 + n*16 + l16] = f2b(oacc[n][r]*invl);
  }
}

// ---------------- launch ----------------
extern "C" void kernel_launch(void* const* d_in, const int* in_sizes, int n_in,
                              void* d_out, int out_size, void* d_ws, size_t ws_size,
                              hipStream_t stream){
  const float* hidden = (const float*)d_in[0];
  const float* wqkv   = (const float*)d_in[1];
  const float* wo     = (const float*)d_in[2];
  const int*   pos    = (const int*)d_in[4];
  float* out = (float*)d_out;
  char* ws = (char*)d_ws;

  // workspace layout (112 MiB total)
  u16* hB    = (u16*)(ws);                    // [0,16)   hidden bf16
  u16* wqkvB = (u16*)(ws + (16ull<<20));      // [16,64)  wqkv bf16 (dead after gemm1)
  u16* woB   = (u16*)(ws + (16ull<<20));      // [16,48)  alias: wo bf16
  u16* qkvB  = (u16*)(ws + (64ull<<20));      // [64,88)  qkv bf16 (dead after rope+vt)
  u16* attnB = (u16*)(ws + (64ull<<20));      // [64,80)  alias: attn out bf16
  u16* Qb    = (u16*)(ws + (88ull<<20));      // [88,104)
  u16* Kb    = (u16*)(ws + (104ull<<20));     // [104,108)
  u16* Vtb   = (u16*)(ws + (108ull<<20));     // [108,112)

  cvt_bf16<<<dim3(8192),  256, 0, stream>>>(hidden, hB, 2097152);
  cvt_bf16<<<dim3(24576), 256, 0, stream>>>(wqkv, wqkvB, 6291456);
  gemm_bt<u16><<<dim3(48,16), 256, 0, stream>>>(hB, wqkvB, qkvB, NQKV, HID);
  cvt_bf16<<<dim3(16384), 256, 0, stream>>>(wo, woB, 4194304);   // overwrites wqkvB (dead)
  rope_reorg<<<dim3(512), 256, 0, stream>>>(qkvB, pos, Qb, Kb);
  v_transpose<<<dim3(32,2,8), 256, 0, stream>>>(qkvB, Vtb);
  attn_fwd<<<dim3(32,32), 256, 0, stream>>>(Qb, Kb, Vtb, attnB);
  gemm_bt<float><<<dim3(32,16), 256, 0, stream>>>(attnB, woB, out, HID, HID);
}